// Round 5
// baseline (176.450 us; speedup 1.0000x reference)
//
#include <hip/hip_runtime.h>

// B=128, V=300, MAX_VISITS=510, D=256, VOCAB=50000, MAX_DAYS=365.
#define MAXV 510
#define D4 64  // D/4 output float4 slots per row

typedef float floatx4 __attribute__((ext_vector_type(4)));

// Fast sin/cos: radians -> revolutions, fract (v_sin_f32 takes revolutions).
// Max arg = 364 rad = 57.9 rev; fp32 reduction error ~2e-5 rad -- far below
// the test threshold.
__device__ __forceinline__ float fast_sin(float x) {
    float r = x * 0.15915494309189535f;
    r = r - floorf(r);
    return __builtin_amdgcn_sinf(r);
}
__device__ __forceinline__ float fast_cos(float x) {
    float r = x * 0.15915494309189535f;
    r = r - floorf(r);
    return __builtin_amdgcn_cosf(r);
}

__device__ __forceinline__ int lower_bound_i(const int* __restrict__ a,
                                             int lo, int hi, int key) {
    while (lo < hi) {
        int m = (lo + hi) >> 1;
        if (a[m] < key) lo = m + 1; else hi = m;
    }
    return lo;
}

// ---- Kernel 0 (prep_rec): per-slot 64B record. NO table convert --
// round-4 post-mortem: the 77MB fp32->bf16 convert (serialized before the
// gather kernel) cost more than the bf16 rows saved in the gather, whose
// traffic is mostly L3-served anyway. fused now gathers fp32 directly.
//
// rec64[slot] = 16 uints:
//   w[0] = bitcast(time)
//   w[1] = (cnt << 26) | code0      (inline form, cnt <= 15; codes < 2^26)
//        = (31  << 26) | lo         (overflow form, cnt > 15; cnt in w[2])
//   w[2..15] = codes[1..14]         (inline form)
// No init needed: d_ws is re-poisoned to 0xAA before every launch (harness
// contract); poison w[1] = 0xAAAAAAAA < 0 encodes "pad".
__global__ __launch_bounds__(256) void prep_rec(
    const int* __restrict__ all_codes,
    const int* __restrict__ c2v,
    const int* __restrict__ person,
    const int* __restrict__ slot,
    const float* __restrict__ times,
    uint4* __restrict__ rec,   // [B*MAXV * 4] (poison = pad)
    int total_codes, int total_visits)
{
    const int i = blockIdx.x * blockDim.x + threadIdx.x;
    if (i >= total_visits) return;

    const int lo = lower_bound_i(c2v, 0, total_codes, i);
    const int hi = lower_bound_i(c2v, lo, total_codes, i + 1);
    const int cnt = hi - lo;

    unsigned int w[16];
    w[0] = __builtin_bit_cast(unsigned int, times[i]);
    if (cnt <= 15) {
        const unsigned int c0 = (cnt > 0) ? (unsigned int)all_codes[lo] : 0u;
        w[1] = ((unsigned int)cnt << 26) | (c0 & 0x3FFFFFFu);
        #pragma unroll
        for (int k = 1; k < 15; ++k)
            w[k + 1] = (k < cnt) ? (unsigned int)all_codes[lo + k] : 0u;
    } else {
        w[1] = (31u << 26) | ((unsigned int)lo & 0x3FFFFFFu);
        w[2] = (unsigned int)cnt;
        #pragma unroll
        for (int k = 3; k < 16; ++k) w[k] = 0u;
    }

    uint4* dst = rec + (size_t)(person[i] * MAXV + slot[i]) * 4;
    dst[0] = make_uint4(w[0],  w[1],  w[2],  w[3]);
    dst[1] = make_uint4(w[4],  w[5],  w[6],  w[7]);
    dst[2] = make_uint4(w[8],  w[9],  w[10], w[11]);
    dst[3] = make_uint4(w[12], w[13], w[14], w[15]);
}

// ---- Kernel 1: fused pad-fill + segment-sum + time embedding (fp32) ----
// One wave per slot. Critical path is TWO memory rounds:
//   1) 64B rec64 load (lanes 0..15 hold the 16 words; rest duplicate)
//   2) up to 16 whole-row gathers, ALL issued at once. Row = 1KB fp32;
//      lane loads its own float4 (dims 4*lane..4*lane+3) => one wave load
//      instruction covers one full row, perfectly coalesced. Rows past
//      rmax clamp to rmax -> duplicate loads are L1 hits.
// No half-wave split, no bf16 unpack, no cross-lane combine: lane owns its
// 4 dims across all rows (16 x 4 adds). Time embedding (v_sin/v_cos)
// overlaps the gathers.
// EXEC DISCIPLINE: every __shfl sits in straight-line code inside
// wave-uniform branches only (round-3 lesson: divergent-guarded
// ds_bpermute reads inactive source lanes => undefined). code(r) for r=0
// comes from pre-masking lane 1's word (cw), not a divergent ternary.
__global__ __launch_bounds__(256) void fused(
    const int* __restrict__ all_codes,    // only for the cnt>15 overflow path
    const floatx4* __restrict__ emb,      // [VOCAB, D4] fp32
    const floatx4* __restrict__ pad,      // [D4]
    const floatx4* __restrict__ tsc,      // [32]
    const unsigned int* __restrict__ rec, // [nslots*16]
    floatx4* __restrict__ out,
    int nslots)
{
    const int tid = threadIdx.x;
    const int w = tid >> 6;
    const int lane = tid & 63;
    const int slot_id = blockIdx.x * 4 + w;
    if (slot_id >= nslots) return;        // wave-uniform

    const unsigned int myw = rec[(size_t)slot_id * 16 + (lane & 15)];
    // cw: lane holding w[1] pre-masked to bare code0, so shfl(cw, r+1)
    // yields code(r) for ALL r in [0, 14] with no special case.
    const unsigned int cw = ((lane & 15) == 1) ? (myw & 0x3FFFFFFu) : myw;

    const int w1 = __shfl((int)myw, 1);
    if (w1 < 0) {                         // wave-uniform (slot-based)
        __builtin_nontemporal_store(pad[lane], &out[slot_id * D4 + lane]);
        return;
    }

    const unsigned int tag = ((unsigned int)w1) >> 26;
    floatx4 acc = (floatx4)(0.f);

    if (tag != 31u) {                     // wave-uniform
        const int cnt = (int)tag;         // inline codes, cnt in [0,15]
        if (cnt > 0) {                    // wave-uniform
            const int rmax = cnt - 1;
            const int c0  = (int)__shfl((int)cw, min(0,  rmax) + 1);
            const int c1  = (int)__shfl((int)cw, min(1,  rmax) + 1);
            const int c2  = (int)__shfl((int)cw, min(2,  rmax) + 1);
            const int c3  = (int)__shfl((int)cw, min(3,  rmax) + 1);
            const int c4  = (int)__shfl((int)cw, min(4,  rmax) + 1);
            const int c5  = (int)__shfl((int)cw, min(5,  rmax) + 1);
            const int c6  = (int)__shfl((int)cw, min(6,  rmax) + 1);
            const int c7  = (int)__shfl((int)cw, min(7,  rmax) + 1);
            const int c8  = (int)__shfl((int)cw, min(8,  rmax) + 1);
            const int c9  = (int)__shfl((int)cw, min(9,  rmax) + 1);
            const int c10 = (int)__shfl((int)cw, min(10, rmax) + 1);
            const int c11 = (int)__shfl((int)cw, min(11, rmax) + 1);
            const int c12 = (int)__shfl((int)cw, min(12, rmax) + 1);
            const int c13 = (int)__shfl((int)cw, min(13, rmax) + 1);
            const int c14 = (int)__shfl((int)cw, min(14, rmax) + 1);
            // All 16 row loads issued together (one memory round).
            const floatx4 e0  = emb[(size_t)c0  * D4 + lane];
            const floatx4 e1  = emb[(size_t)c1  * D4 + lane];
            const floatx4 e2  = emb[(size_t)c2  * D4 + lane];
            const floatx4 e3  = emb[(size_t)c3  * D4 + lane];
            const floatx4 e4  = emb[(size_t)c4  * D4 + lane];
            const floatx4 e5  = emb[(size_t)c5  * D4 + lane];
            const floatx4 e6  = emb[(size_t)c6  * D4 + lane];
            const floatx4 e7  = emb[(size_t)c7  * D4 + lane];
            const floatx4 e8  = emb[(size_t)c8  * D4 + lane];
            const floatx4 e9  = emb[(size_t)c9  * D4 + lane];
            const floatx4 e10 = emb[(size_t)c10 * D4 + lane];
            const floatx4 e11 = emb[(size_t)c11 * D4 + lane];
            const floatx4 e12 = emb[(size_t)c12 * D4 + lane];
            const floatx4 e13 = emb[(size_t)c13 * D4 + lane];
            const floatx4 e14 = emb[(size_t)c14 * D4 + lane];
            // cnt is wave-uniform; guards are uniform per unrolled step.
            acc += e0;
            if (cnt > 1)  acc += e1;
            if (cnt > 2)  acc += e2;
            if (cnt > 3)  acc += e3;
            if (cnt > 4)  acc += e4;
            if (cnt > 5)  acc += e5;
            if (cnt > 6)  acc += e6;
            if (cnt > 7)  acc += e7;
            if (cnt > 8)  acc += e8;
            if (cnt > 9)  acc += e9;
            if (cnt > 10) acc += e10;
            if (cnt > 11) acc += e11;
            if (cnt > 12) acc += e12;
            if (cnt > 13) acc += e13;
            if (cnt > 14) acc += e14;
        }
    } else {
        // Overflow path (cnt > 15): codes from all_codes. Never taken with
        // this data shape; kept for correctness. Branch is wave-uniform.
        const int lo = w1 & 0x3FFFFFF;
        const int cnt = (int)__shfl((int)myw, 2);
        for (int j = 0; j < cnt; ++j) {
            const int c = all_codes[lo + j];
            acc += emb[(size_t)c * D4 + lane];
        }
    }

    // Time embedding: depends only on rec word 0; compiler schedules the
    // trig under the outstanding gathers. Lane f=lane covers dims
    // 4f..4f+3: f<32 -> sin(t*ts[f]), f>=32 -> cos(t*ts[f-32]).
    float t = __builtin_bit_cast(float, __shfl((int)myw, 0));
    t = fminf(fmaxf(t, 0.f), 364.f);
    const floatx4 ts = tsc[lane & 31];
    floatx4 tv;
    if (lane < 32) {
        tv.x = fast_sin(t * ts.x); tv.y = fast_sin(t * ts.y);
        tv.z = fast_sin(t * ts.z); tv.w = fast_sin(t * ts.w);
    } else {
        tv.x = fast_cos(t * ts.x); tv.y = fast_cos(t * ts.y);
        tv.z = fast_cos(t * ts.z); tv.w = fast_cos(t * ts.w);
    }
    acc += tv;

    __builtin_nontemporal_store(acc, &out[slot_id * D4 + lane]);
}

extern "C" void kernel_launch(void* const* d_in, const int* in_sizes, int n_in,
                              void* d_out, int out_size, void* d_ws, size_t ws_size,
                              hipStream_t stream) {
    const int*   all_codes = (const int*)d_in[0];
    const int*   c2v       = (const int*)d_in[1];
    const int*   person    = (const int*)d_in[2];
    const int*   slot      = (const int*)d_in[3];
    const float* times     = (const float*)d_in[4];
    const float* emb       = (const float*)d_in[5];
    const float* pad       = (const float*)d_in[6];
    const float* tsc       = (const float*)d_in[7];

    const int total_codes  = in_sizes[0];
    const int total_visits = in_sizes[2];
    const int nslots       = out_size / 256;   // B * MAXV

    uint4* rec = (uint4*)d_ws;                 // [nslots*4] (poison = pad)
    (void)ws_size;                             // needs only nslots*64 = 4.2 MB

    prep_rec<<<(total_visits + 255) / 256, 256, 0, stream>>>(
        all_codes, c2v, person, slot, times, rec,
        total_codes, total_visits);

    fused<<<(nslots + 3) / 4, 256, 0, stream>>>(
        all_codes, (const floatx4*)emb, (const floatx4*)pad,
        (const floatx4*)tsc, (const unsigned int*)rec,
        (floatx4*)d_out, nslots);
}

// Round 6
// 166.067 us; speedup vs baseline: 1.0625x; 1.0625x over previous
//
#include <hip/hip_runtime.h>

// B=128, V=300, MAX_VISITS=510, D=256, VOCAB=50000, MAX_DAYS=365.
#define MAXV 510
#define D4 64  // D/4 output float4 slots per row

typedef float floatx4 __attribute__((ext_vector_type(4)));

__device__ __forceinline__ unsigned int pack2_bf16_rne(float a, float b) {
    unsigned int ua = __builtin_bit_cast(unsigned int, a);
    unsigned int ub = __builtin_bit_cast(unsigned int, b);
    ua = (ua + 0x7FFFu + ((ua >> 16) & 1u)) >> 16;
    ub = (ub + 0x7FFFu + ((ub >> 16) & 1u)) >> 16;
    return ua | (ub << 16);
}

__device__ __forceinline__ float bf_lo(unsigned int u) {
    return __builtin_bit_cast(float, u << 16);
}
__device__ __forceinline__ float bf_hi(unsigned int u) {
    return __builtin_bit_cast(float, u & 0xFFFF0000u);
}

// Accumulate 8 bf16 dims (uint4) into two float4 partials.
__device__ __forceinline__ void acc8(floatx4& a0, floatx4& a1, uint4 u) {
    a0.x += bf_lo(u.x); a0.y += bf_hi(u.x);
    a0.z += bf_lo(u.y); a0.w += bf_hi(u.y);
    a1.x += bf_lo(u.z); a1.y += bf_hi(u.z);
    a1.z += bf_lo(u.w); a1.w += bf_hi(u.w);
}

// Fast sin/cos: radians -> revolutions, fract (v_sin_f32 takes revolutions).
// Max arg = 364 rad = 57.9 rev; fp32 reduction error ~2e-5 rad, negligible
// vs bf16-table absmax (0.125).
__device__ __forceinline__ float fast_sin(float x) {
    float r = x * 0.15915494309189535f;
    r = r - floorf(r);
    return __builtin_amdgcn_sinf(r);
}
__device__ __forceinline__ float fast_cos(float x) {
    float r = x * 0.15915494309189535f;
    r = r - floorf(r);
    return __builtin_amdgcn_cosf(r);
}

__device__ __forceinline__ int lower_bound_i(const int* __restrict__ a,
                                             int lo, int hi, int key) {
    while (lo < hi) {
        int m = (lo + hi) >> 1;
        if (a[m] < key) lo = m + 1; else hi = m;
    }
    return lo;
}

// ---- Kernel 0 (prep): fp32->bf16 table convert + per-slot 64B record.
// Round-5 lesson: the bf16 table HALVES gather FETCH (98.5 vs 205.9 MB) and
// the gather is traffic-proportional -> the convert pays for itself. Keep it.
// rec64[slot] = 16 uints:
//   w[0] = bitcast(time)
//   w[1] = (cnt << 26) | code0      (inline form, cnt <= 15; codes < 2^26)
//        = (31  << 26) | lo         (overflow form, cnt > 15; cnt in w[2])
//   w[2..15] = codes[1..14]         (inline form)
// No init needed: d_ws is re-poisoned to 0xAA before every launch (harness
// contract); poison w[1] = 0xAAAAAAAA < 0 encodes "pad".
__global__ __launch_bounds__(256) void prep(
    const floatx4* __restrict__ in, uint4* __restrict__ outtab, int npairs,
    const int* __restrict__ all_codes,
    const int* __restrict__ c2v,
    const int* __restrict__ person,
    const int* __restrict__ slot,
    const float* __restrict__ times,
    uint4* __restrict__ rec,   // [B*MAXV * 4] (poison = pad)
    int total_codes, int total_visits)
{
    const int i = blockIdx.x * blockDim.x + threadIdx.x;

    if (i < total_visits) {
        const int lo = lower_bound_i(c2v, 0, total_codes, i);
        const int hi = lower_bound_i(c2v, lo, total_codes, i + 1);
        const int cnt = hi - lo;

        unsigned int w[16];
        w[0] = __builtin_bit_cast(unsigned int, times[i]);
        if (cnt <= 15) {
            const unsigned int c0 = (cnt > 0) ? (unsigned int)all_codes[lo] : 0u;
            w[1] = ((unsigned int)cnt << 26) | (c0 & 0x3FFFFFFu);
            #pragma unroll
            for (int k = 1; k < 15; ++k)
                w[k + 1] = (k < cnt) ? (unsigned int)all_codes[lo + k] : 0u;
        } else {
            w[1] = (31u << 26) | ((unsigned int)lo & 0x3FFFFFFu);
            w[2] = (unsigned int)cnt;
            #pragma unroll
            for (int k = 3; k < 16; ++k) w[k] = 0u;
        }

        uint4* dst = rec + (size_t)(person[i] * MAXV + slot[i]) * 4;
        dst[0] = make_uint4(w[0],  w[1],  w[2],  w[3]);
        dst[1] = make_uint4(w[4],  w[5],  w[6],  w[7]);
        dst[2] = make_uint4(w[8],  w[9],  w[10], w[11]);
        dst[3] = make_uint4(w[12], w[13], w[14], w[15]);
    }

    if (i < npairs) {
        // Streamed once; nontemporal read so the 51 MB fp32 table doesn't
        // evict the bf16 table (which fused_bf16 wants resident in L2/L3).
        const floatx4 a = __builtin_nontemporal_load(&in[2 * i]);
        const floatx4 b = __builtin_nontemporal_load(&in[2 * i + 1]);
        uint4 r;
        r.x = pack2_bf16_rne(a.x, a.y);
        r.y = pack2_bf16_rne(a.z, a.w);
        r.z = pack2_bf16_rne(b.x, b.y);
        r.w = pack2_bf16_rne(b.z, b.w);
        outtab[i] = r;
    }
}

// ---- Kernel 1: PERSISTENT fused pad-fill + segment-sum + time emb ----
// Round-5 post-mortem: one-shot waves are latency-bound (HBM read only
// 2.4 TB/s, VALU ~50% -- neither pipe saturated; wave life = rec round +
// gather round + VALU). This version: each wave owns SPW consecutive slots
// and software-pipelines them -- prefetch rec64[s+1] while slot s's
// gathers/VALU are in flight, so only the FIRST slot pays the rec round.
// pad[lane] and tsc[f] are hoisted: pad slots (41% of all slots) become
// pure 1KB stores.
// EXEC DISCIPLINE (round-3 lesson): every __shfl sits in straight-line
// code inside wave-uniform branches only; code(r) for r=0 comes from
// pre-masking lane 1's word (cw), never a divergent ternary.
__global__ __launch_bounds__(256) void fused_bf16(
    const int* __restrict__ all_codes,   // only for the cnt>15 overflow path
    const uint4* __restrict__ embh,      // [VOCAB, 32] 16B chunks
    const floatx4* __restrict__ pad,     // [D4]
    const floatx4* __restrict__ tsc,     // [32]
    const unsigned int* __restrict__ rec,// [nslots*16]
    floatx4* __restrict__ out,
    int nslots, int spw)
{
    const int tid = threadIdx.x;
    const int lane = tid & 63;
    const int half = lane >> 5;
    const int hl = lane & 31;
    const int wave = blockIdx.x * (blockDim.x >> 6) + (tid >> 6);

    int s = wave * spw;
    const int s_end = min(s + spw, nslots);
    if (s >= s_end) return;               // wave-uniform

    // Loop-invariant hoists.
    const floatx4 pv = pad[lane];
    const int f = 2 * hl + half;          // output float4 slot
    const floatx4 ts = tsc[f & 31];

    // Prologue: rec64 for the first slot.
    unsigned int cur = rec[(size_t)s * 16 + (lane & 15)];

    for (; s < s_end; ++s) {
        // Prefetch next slot's rec64; independent of everything below, so
        // it stays in flight across this iteration's gathers and VALU.
        unsigned int nxt = 0u;
        if (s + 1 < s_end)                // wave-uniform
            nxt = rec[(size_t)(s + 1) * 16 + (lane & 15)];

        // cw: lane holding w[1] pre-masked to bare code0, so shfl(cw, r+1)
        // yields code(r) for ALL r in [0,14] with no special case.
        const unsigned int cw = ((lane & 15) == 1) ? (cur & 0x3FFFFFFu) : cur;
        const int w1 = __shfl((int)cur, 1);

        if (w1 < 0) {                     // wave-uniform: pad slot
            __builtin_nontemporal_store(pv, &out[(size_t)s * D4 + lane]);
        } else {
            const unsigned int tag = ((unsigned int)w1) >> 26;
            floatx4 acc0 = (floatx4)(0.f);
            floatx4 acc1 = (floatx4)(0.f);

            if (tag != 31u) {             // wave-uniform
                const int cnt = (int)tag; // inline codes, cnt in [0,15]
                if (cnt > 0) {            // wave-uniform
                    const int rmax = cnt - 1;
                    // rows r = min(2i+half, rmax); code(r) = shfl(cw, r+1)
                    const int c0 = (int)__shfl((int)cw, min(half,      rmax) + 1);
                    const int c1 = (int)__shfl((int)cw, min(2 + half,  rmax) + 1);
                    const int c2 = (int)__shfl((int)cw, min(4 + half,  rmax) + 1);
                    const int c3 = (int)__shfl((int)cw, min(6 + half,  rmax) + 1);
                    const int c4 = (int)__shfl((int)cw, min(8 + half,  rmax) + 1);
                    const int c5 = (int)__shfl((int)cw, min(10 + half, rmax) + 1);
                    const int c6 = (int)__shfl((int)cw, min(12 + half, rmax) + 1);
                    const int c7 = (int)__shfl((int)cw, min(14 + half, rmax) + 1);
                    // All 8 pair-gathers issued together (one memory round);
                    // half-wave h covers row 2i+h at 16B/lane (8 bf16 dims).
                    const uint4 e0 = embh[(size_t)c0 * 32 + hl];
                    const uint4 e1 = embh[(size_t)c1 * 32 + hl];
                    const uint4 e2 = embh[(size_t)c2 * 32 + hl];
                    const uint4 e3 = embh[(size_t)c3 * 32 + hl];
                    const uint4 e4 = embh[(size_t)c4 * 32 + hl];
                    const uint4 e5 = embh[(size_t)c5 * 32 + hl];
                    const uint4 e6 = embh[(size_t)c6 * 32 + hl];
                    const uint4 e7 = embh[(size_t)c7 * 32 + hl];
                    if (half      < cnt) acc8(acc0, acc1, e0);
                    if (2 + half  < cnt) acc8(acc0, acc1, e1);
                    if (4 + half  < cnt) acc8(acc0, acc1, e2);
                    if (6 + half  < cnt) acc8(acc0, acc1, e3);
                    if (8 + half  < cnt) acc8(acc0, acc1, e4);
                    if (10 + half < cnt) acc8(acc0, acc1, e5);
                    if (12 + half < cnt) acc8(acc0, acc1, e6);
                    if (14 + half < cnt) acc8(acc0, acc1, e7);
                }
            } else {
                // Overflow path (cnt > 15): never taken with this data
                // shape; kept for correctness. Branch is wave-uniform.
                const int lo = w1 & 0x3FFFFFF;
                const int cnt = (int)__shfl((int)cur, 2);
                for (int j = 0; j < cnt; j += 2) {
                    const int jj = min(j + half, cnt - 1);
                    const int c = all_codes[lo + jj];
                    const uint4 e = embh[(size_t)c * 32 + hl];
                    if (j + half < cnt) acc8(acc0, acc1, e);
                }
            }

            // Time embedding; overlaps the outstanding gathers.
            float t = __builtin_bit_cast(float, __shfl((int)cur, 0));
            t = fminf(fmaxf(t, 0.f), 364.f);
            floatx4 tv;
            if (f < 32) {
                tv.x = fast_sin(t * ts.x); tv.y = fast_sin(t * ts.y);
                tv.z = fast_sin(t * ts.z); tv.w = fast_sin(t * ts.w);
            } else {
                tv.x = fast_cos(t * ts.x); tv.y = fast_cos(t * ts.y);
                tv.z = fast_cos(t * ts.z); tv.w = fast_cos(t * ts.w);
            }

            // Combine half-wave partials.
            acc0.x += __shfl_xor(acc0.x, 32); acc0.y += __shfl_xor(acc0.y, 32);
            acc0.z += __shfl_xor(acc0.z, 32); acc0.w += __shfl_xor(acc0.w, 32);
            acc1.x += __shfl_xor(acc1.x, 32); acc1.y += __shfl_xor(acc1.y, 32);
            acc1.z += __shfl_xor(acc1.z, 32); acc1.w += __shfl_xor(acc1.w, 32);

            floatx4 r = half ? acc1 : acc0;
            r.x += tv.x; r.y += tv.y; r.z += tv.z; r.w += tv.w;

            __builtin_nontemporal_store(r, &out[(size_t)s * D4 + f]);
        }

        cur = nxt;
    }
}

// ---- fp32 fallback (only if ws too small for rec + bf16 table) ----
__global__ __launch_bounds__(256) void build_maps(
    const int* __restrict__ c2v,
    const int* __restrict__ person,
    const int* __restrict__ slot,
    int* __restrict__ inv,
    int* __restrict__ off,
    int total_codes, int total_visits)
{
    int v = blockIdx.x * blockDim.x + threadIdx.x;
    if (v >= total_visits) return;
    inv[person[v] * MAXV + slot[v]] = v;
    int lo = 0, hi = total_codes;
    while (lo < hi) {
        int m = (lo + hi) >> 1;
        if (c2v[m] < v) lo = m + 1; else hi = m;
    }
    off[v] = lo;
    if (v == 0) off[total_visits] = total_codes;
}

__global__ __launch_bounds__(256) void fused_f32(
    const int* __restrict__ all_codes,
    const float* __restrict__ times,
    const floatx4* __restrict__ emb,
    const floatx4* __restrict__ pad,
    const floatx4* __restrict__ tsc,
    const int* __restrict__ inv,
    const int* __restrict__ off,
    floatx4* __restrict__ out,
    int nslots)
{
    const int tid = threadIdx.x;
    const int w = tid >> 6;
    const int lane = tid & 63;
    const int slot_id = blockIdx.x * 4 + w;
    if (slot_id >= nslots) return;

    const int v = inv[slot_id];
    if (v < 0) {
        __builtin_nontemporal_store(pad[lane], &out[slot_id * D4 + lane]);
        return;
    }
    const int lo = off[v];
    const int hi = off[v + 1];

    float t = times[v];
    t = fminf(fmaxf(t, 0.f), 364.f);
    const floatx4 ts = tsc[lane & 31];
    floatx4 acc;
    if (lane < 32) {
        acc.x = sinf(t * ts.x); acc.y = sinf(t * ts.y);
        acc.z = sinf(t * ts.z); acc.w = sinf(t * ts.w);
    } else {
        acc.x = cosf(t * ts.x); acc.y = cosf(t * ts.y);
        acc.z = cosf(t * ts.z); acc.w = cosf(t * ts.w);
    }
    for (int i = lo; i < hi; ++i)
        acc += emb[(size_t)all_codes[i] * D4 + lane];
    __builtin_nontemporal_store(acc, &out[slot_id * D4 + lane]);
}

extern "C" void kernel_launch(void* const* d_in, const int* in_sizes, int n_in,
                              void* d_out, int out_size, void* d_ws, size_t ws_size,
                              hipStream_t stream) {
    const int*   all_codes = (const int*)d_in[0];
    const int*   c2v       = (const int*)d_in[1];
    const int*   person    = (const int*)d_in[2];
    const int*   slot      = (const int*)d_in[3];
    const float* times     = (const float*)d_in[4];
    const float* emb       = (const float*)d_in[5];
    const float* pad       = (const float*)d_in[6];
    const float* tsc       = (const float*)d_in[7];

    const int total_codes  = in_sizes[0];
    const int total_visits = in_sizes[2];
    const int emb_elems    = in_sizes[5];      // VOCAB * D
    const int nslots       = out_size / 256;   // B * MAXV

    char* ws = (char*)d_ws;
    uint4* rec = (uint4*)ws;                   // [nslots*4] (poison = pad)
    size_t head = ((size_t)nslots * 64 + 255) & ~(size_t)255;
    unsigned short* embh = (unsigned short*)(ws + head);
    const size_t needed = head + (size_t)emb_elems * sizeof(unsigned short);

    if (ws_size >= needed) {
        const int npairs = emb_elems / 8;
        const int nthreads = max(npairs, total_visits);
        prep<<<(nthreads + 255) / 256, 256, 0, stream>>>(
            (const floatx4*)emb, (uint4*)embh, npairs,
            all_codes, c2v, person, slot, times, rec,
            total_codes, total_visits);

        // Persistent fused: ~8 slots per wave, 4 waves per 256-thr block.
        const int spw = 8;
        const int nwaves  = (nslots + spw - 1) / spw;
        const int nblocks = (nwaves + 3) / 4;
        fused_bf16<<<nblocks, 256, 0, stream>>>(
            all_codes, (const uint4*)embh, (const floatx4*)pad,
            (const floatx4*)tsc, (const unsigned int*)rec,
            (floatx4*)d_out, nslots, spw);
    } else {
        int* inv = (int*)ws;
        int* off = inv + nslots;
        (void)hipMemsetAsync(inv, 0xFF, (size_t)nslots * sizeof(int), stream);
        build_maps<<<(total_visits + 255) / 256, 256, 0, stream>>>(
            c2v, person, slot, inv, off, total_codes, total_visits);
        fused_f32<<<(nslots + 3) / 4, 256, 0, stream>>>(
            all_codes, times, (const floatx4*)emb, (const floatx4*)pad,
            (const floatx4*)tsc, inv, off, (floatx4*)d_out, nslots);
    }
}

// Round 7
// 155.730 us; speedup vs baseline: 1.1330x; 1.0664x over previous
//
#include <hip/hip_runtime.h>

// B=128, V=300, MAX_VISITS=510, D=256, VOCAB=50000, MAX_DAYS=365.
#define MAXV 510
#define D4 64  // D/4 output float4 slots per row

typedef float floatx4 __attribute__((ext_vector_type(4)));

__device__ __forceinline__ unsigned int pack2_bf16_rne(float a, float b) {
    unsigned int ua = __builtin_bit_cast(unsigned int, a);
    unsigned int ub = __builtin_bit_cast(unsigned int, b);
    ua = (ua + 0x7FFFu + ((ua >> 16) & 1u)) >> 16;
    ub = (ub + 0x7FFFu + ((ub >> 16) & 1u)) >> 16;
    return ua | (ub << 16);
}

__device__ __forceinline__ float bf_lo(unsigned int u) {
    return __builtin_bit_cast(float, u << 16);
}
__device__ __forceinline__ float bf_hi(unsigned int u) {
    return __builtin_bit_cast(float, u & 0xFFFF0000u);
}

// Accumulate 8 bf16 dims (uint4) into two float4 partials.
__device__ __forceinline__ void acc8(floatx4& a0, floatx4& a1, uint4 u) {
    a0.x += bf_lo(u.x); a0.y += bf_hi(u.x);
    a0.z += bf_lo(u.y); a0.w += bf_hi(u.y);
    a1.x += bf_lo(u.z); a1.y += bf_hi(u.z);
    a1.z += bf_lo(u.w); a1.w += bf_hi(u.w);
}

// Fast sin/cos: radians -> revolutions, fract (v_sin_f32 takes revolutions).
// Max arg = 364 rad = 57.9 rev; fp32 reduction error ~2e-5 rad, negligible
// vs bf16-table absmax (0.125).
__device__ __forceinline__ float fast_sin(float x) {
    float r = x * 0.15915494309189535f;
    r = r - floorf(r);
    return __builtin_amdgcn_sinf(r);
}
__device__ __forceinline__ float fast_cos(float x) {
    float r = x * 0.15915494309189535f;
    r = r - floorf(r);
    return __builtin_amdgcn_cosf(r);
}

__device__ __forceinline__ int lower_bound_i(const int* __restrict__ a,
                                             int lo, int hi, int key) {
    while (lo < hi) {
        int m = (lo + hi) >> 1;
        if (a[m] < key) lo = m + 1; else hi = m;
    }
    return lo;
}

// ---- Kernel 0 (prep): fp32->bf16 table convert + slot->visit 16B record.
// rec[slot] = {lo, cnt, bitcast(time), 0}. No init needed: d_ws is
// re-poisoned to 0xAA before every launch (harness contract); poison
// rec.x = 0xAAAAAAAA < 0 encodes "pad".
// Second boundary search is CAPPED at lo+16 (cnt <= 15 in this data; the
// second search was a full 19-round dependent chain -- the prep critical
// path at only 38400 threads). Falls back to a full search if saturated,
// preserving correctness for arbitrary cnt.
__global__ __launch_bounds__(256) void prep(
    const floatx4* __restrict__ in, uint4* __restrict__ outtab, int npairs,
    const int* __restrict__ c2v,
    const int* __restrict__ person,
    const int* __restrict__ slot,
    const float* __restrict__ times,
    int4* __restrict__ rec,    // [B*MAXV] (poison = pad)
    int total_codes, int total_visits)
{
    const int i = blockIdx.x * blockDim.x + threadIdx.x;

    if (i < total_visits) {
        const int lo = lower_bound_i(c2v, 0, total_codes, i);
        const int hi_cap = min(lo + 16, total_codes);
        int hi = lower_bound_i(c2v, lo, hi_cap, i + 1);
        if (hi == hi_cap && hi_cap < total_codes && c2v[hi] < i + 1) {
            // cnt >= 16 (never with this data shape): resume full search.
            hi = lower_bound_i(c2v, hi, total_codes, i + 1);
        }
        int4 r;
        r.x = lo;
        r.y = hi - lo;
        r.z = __builtin_bit_cast(int, times[i]);
        r.w = 0;
        rec[person[i] * MAXV + slot[i]] = r;
    }

    if (i < npairs) {
        // Streamed once; nontemporal read so the 51 MB fp32 table doesn't
        // evict the bf16 table (which fused_bf16 wants resident in L2/L3).
        const floatx4 a = __builtin_nontemporal_load(&in[2 * i]);
        const floatx4 b = __builtin_nontemporal_load(&in[2 * i + 1]);
        uint4 r;
        r.x = pack2_bf16_rne(a.x, a.y);
        r.y = pack2_bf16_rne(a.z, a.w);
        r.z = pack2_bf16_rne(b.x, b.y);
        r.w = pack2_bf16_rne(b.z, b.w);
        outtab[i] = r;
    }
}

// ---- Kernel 1: fused pad-fill + segment-sum + time embedding (bf16) ----
// One wave per slot (one-shot: 65280 waves of TLP -- round-6 lesson:
// persistence starves occupancy and loses). Critical path: rec (1 load) ->
// codes (1 load) -> ONE gather round (cnt wave-uniform; cnt<=8 -> 4
// pair-loads, cnt<=16 -> 8 pair-loads, all in flight at once). Pair-row
// gather: half-wave h loads row r+h at 16B/lane (uint4 = 8 bf16 dims); one
// 1KB load instruction covers 2 rows. Time embedding (v_sin/v_cos) is
// computed while the codes load is outstanding. shfl_xor(32) combines
// half-wave partials; lane stores output float4 slot f = 2*(lane&31)+half.
// EXEC DISCIPLINE (round-3 lesson): every __shfl sits in straight-line
// code inside wave-uniform branches only.
__global__ __launch_bounds__(256) void fused_bf16(
    const int* __restrict__ all_codes,
    const uint4* __restrict__ embh,   // [VOCAB, 32] 16B chunks
    const floatx4* __restrict__ pad,  // [D4]
    const floatx4* __restrict__ tsc,  // [32]
    const int4* __restrict__ rec,     // [nslots]
    floatx4* __restrict__ out,
    int nslots)
{
    const int tid = threadIdx.x;
    const int w = tid >> 6;
    const int lane = tid & 63;
    const int half = lane >> 5;
    const int hl = lane & 31;
    const int slot_id = blockIdx.x * 4 + w;
    if (slot_id >= nslots) return;

    const int4 rc = rec[slot_id];
    if (rc.x < 0) {
        __builtin_nontemporal_store(pad[lane], &out[slot_id * D4 + lane]);
        return;
    }
    const int lo = rc.x;
    const int cnt = rc.y;
    const int rmax = cnt - 1;

    // Issue codes load first; everything below until the shfl is independent.
    int mycode = 0;
    if (cnt > 0) mycode = all_codes[lo + min(lane, rmax)];

    // Time embedding: depends only on rec, overlaps the codes load.
    const int f = 2 * hl + half;               // output float4 slot
    float t = __builtin_bit_cast(float, rc.z);
    t = fminf(fmaxf(t, 0.f), 364.f);
    const floatx4 ts = tsc[f & 31];
    floatx4 tv;
    if (f < 32) {
        tv.x = fast_sin(t * ts.x); tv.y = fast_sin(t * ts.y);
        tv.z = fast_sin(t * ts.z); tv.w = fast_sin(t * ts.w);
    } else {
        tv.x = fast_cos(t * ts.x); tv.y = fast_cos(t * ts.y);
        tv.z = fast_cos(t * ts.z); tv.w = fast_cos(t * ts.w);
    }

    floatx4 acc0 = (floatx4)(0.f);
    floatx4 acc1 = (floatx4)(0.f);

    if (cnt > 0) {
        if (cnt <= 16) {                       // hot: cnt in [8,15]
            if (cnt <= 8) {
                const int c0 = __shfl(mycode, min(half,     rmax));
                const int c1 = __shfl(mycode, min(2 + half, rmax));
                const int c2 = __shfl(mycode, min(4 + half, rmax));
                const int c3 = __shfl(mycode, min(6 + half, rmax));
                const uint4 e0 = embh[(size_t)c0 * 32 + hl];
                const uint4 e1 = embh[(size_t)c1 * 32 + hl];
                const uint4 e2 = embh[(size_t)c2 * 32 + hl];
                const uint4 e3 = embh[(size_t)c3 * 32 + hl];
                if (half     < cnt) acc8(acc0, acc1, e0);
                if (2 + half < cnt) acc8(acc0, acc1, e1);
                if (4 + half < cnt) acc8(acc0, acc1, e2);
                if (6 + half < cnt) acc8(acc0, acc1, e3);
            } else {
                // rows 0..7 always valid (cnt >= 9): unguarded, unclamped.
                const int c0 = __shfl(mycode, half);
                const int c1 = __shfl(mycode, 2 + half);
                const int c2 = __shfl(mycode, 4 + half);
                const int c3 = __shfl(mycode, 6 + half);
                const int c4 = __shfl(mycode, min(8  + half, rmax));
                const int c5 = __shfl(mycode, min(10 + half, rmax));
                const int c6 = __shfl(mycode, min(12 + half, rmax));
                const int c7 = __shfl(mycode, min(14 + half, rmax));
                const uint4 e0 = embh[(size_t)c0 * 32 + hl];
                const uint4 e1 = embh[(size_t)c1 * 32 + hl];
                const uint4 e2 = embh[(size_t)c2 * 32 + hl];
                const uint4 e3 = embh[(size_t)c3 * 32 + hl];
                const uint4 e4 = embh[(size_t)c4 * 32 + hl];
                const uint4 e5 = embh[(size_t)c5 * 32 + hl];
                const uint4 e6 = embh[(size_t)c6 * 32 + hl];
                const uint4 e7 = embh[(size_t)c7 * 32 + hl];
                acc8(acc0, acc1, e0);
                acc8(acc0, acc1, e1);
                acc8(acc0, acc1, e2);
                acc8(acc0, acc1, e3);
                if (8  + half < cnt) acc8(acc0, acc1, e4);
                if (10 + half < cnt) acc8(acc0, acc1, e5);
                if (12 + half < cnt) acc8(acc0, acc1, e6);
                if (14 + half < cnt) acc8(acc0, acc1, e7);
            }
        } else if (cnt <= 64) {
            for (int j = 0; j < cnt; j += 8) { // 4 pair-loads (8 rows)/iter
                const int j0 = j + half;
                const int j1 = j + 2 + half;
                const int j2 = j + 4 + half;
                const int j3 = j + 6 + half;
                const int c0 = __shfl(mycode, min(j0, rmax));
                const int c1 = __shfl(mycode, min(j1, rmax));
                const int c2 = __shfl(mycode, min(j2, rmax));
                const int c3 = __shfl(mycode, min(j3, rmax));
                const uint4 e0 = embh[(size_t)c0 * 32 + hl];
                const uint4 e1 = embh[(size_t)c1 * 32 + hl];
                const uint4 e2 = embh[(size_t)c2 * 32 + hl];
                const uint4 e3 = embh[(size_t)c3 * 32 + hl];
                if (j0 < cnt) acc8(acc0, acc1, e0);
                if (j1 < cnt) acc8(acc0, acc1, e1);
                if (j2 < cnt) acc8(acc0, acc1, e2);
                if (j3 < cnt) acc8(acc0, acc1, e3);
            }
        } else {
            for (int j = 0; j < cnt; j += 2) { // cold generic path
                const int jj = min(j + half, cnt - 1);
                const int c = all_codes[lo + jj];
                const uint4 e = embh[(size_t)c * 32 + hl];
                if (j + half < cnt) acc8(acc0, acc1, e);
            }
        }
    }

    // Combine half-wave partials (both halves end with full sums).
    acc0.x += __shfl_xor(acc0.x, 32); acc0.y += __shfl_xor(acc0.y, 32);
    acc0.z += __shfl_xor(acc0.z, 32); acc0.w += __shfl_xor(acc0.w, 32);
    acc1.x += __shfl_xor(acc1.x, 32); acc1.y += __shfl_xor(acc1.y, 32);
    acc1.z += __shfl_xor(acc1.z, 32); acc1.w += __shfl_xor(acc1.w, 32);

    floatx4 r = half ? acc1 : acc0;
    r.x += tv.x; r.y += tv.y; r.z += tv.z; r.w += tv.w;

    __builtin_nontemporal_store(r, &out[slot_id * D4 + f]);
}

// ---- fp32 fallback (only if ws too small for the bf16 table) ----
__global__ __launch_bounds__(256) void build_maps(
    const int* __restrict__ c2v,
    const int* __restrict__ person,
    const int* __restrict__ slot,
    int* __restrict__ inv,
    int* __restrict__ off,
    int total_codes, int total_visits)
{
    int v = blockIdx.x * blockDim.x + threadIdx.x;
    if (v >= total_visits) return;
    inv[person[v] * MAXV + slot[v]] = v;
    int lo = 0, hi = total_codes;
    while (lo < hi) {
        int m = (lo + hi) >> 1;
        if (c2v[m] < v) lo = m + 1; else hi = m;
    }
    off[v] = lo;
    if (v == 0) off[total_visits] = total_codes;
}

__global__ __launch_bounds__(256) void fused_f32(
    const int* __restrict__ all_codes,
    const float* __restrict__ times,
    const floatx4* __restrict__ emb,
    const floatx4* __restrict__ pad,
    const floatx4* __restrict__ tsc,
    const int* __restrict__ inv,
    const int* __restrict__ off,
    floatx4* __restrict__ out,
    int nslots)
{
    const int tid = threadIdx.x;
    const int w = tid >> 6;
    const int lane = tid & 63;
    const int slot_id = blockIdx.x * 4 + w;
    if (slot_id >= nslots) return;

    const int v = inv[slot_id];
    if (v < 0) {
        __builtin_nontemporal_store(pad[lane], &out[slot_id * D4 + lane]);
        return;
    }
    const int lo = off[v];
    const int hi = off[v + 1];

    float t = times[v];
    t = fminf(fmaxf(t, 0.f), 364.f);
    const floatx4 ts = tsc[lane & 31];
    floatx4 acc;
    if (lane < 32) {
        acc.x = sinf(t * ts.x); acc.y = sinf(t * ts.y);
        acc.z = sinf(t * ts.z); acc.w = sinf(t * ts.w);
    } else {
        acc.x = cosf(t * ts.x); acc.y = cosf(t * ts.y);
        acc.z = cosf(t * ts.z); acc.w = cosf(t * ts.w);
    }
    for (int i = lo; i < hi; ++i)
        acc += emb[(size_t)all_codes[i] * D4 + lane];
    __builtin_nontemporal_store(acc, &out[slot_id * D4 + lane]);
}

extern "C" void kernel_launch(void* const* d_in, const int* in_sizes, int n_in,
                              void* d_out, int out_size, void* d_ws, size_t ws_size,
                              hipStream_t stream) {
    const int*   all_codes = (const int*)d_in[0];
    const int*   c2v       = (const int*)d_in[1];
    const int*   person    = (const int*)d_in[2];
    const int*   slot      = (const int*)d_in[3];
    const float* times     = (const float*)d_in[4];
    const float* emb       = (const float*)d_in[5];
    const float* pad       = (const float*)d_in[6];
    const float* tsc       = (const float*)d_in[7];

    const int total_codes  = in_sizes[0];
    const int total_visits = in_sizes[2];
    const int emb_elems    = in_sizes[5];      // VOCAB * D
    const int nslots       = out_size / 256;   // B * MAXV

    char* ws = (char*)d_ws;
    int4* rec = (int4*)ws;                     // [nslots] (poison = pad)
    size_t head = ((size_t)nslots * sizeof(int4) + 255) & ~(size_t)255;
    unsigned short* embh = (unsigned short*)(ws + head);
    const size_t needed = head + (size_t)emb_elems * sizeof(unsigned short);

    if (ws_size >= needed) {
        const int npairs = emb_elems / 8;
        const int nthreads = max(npairs, total_visits);
        prep<<<(nthreads + 255) / 256, 256, 0, stream>>>(
            (const floatx4*)emb, (uint4*)embh, npairs,
            c2v, person, slot, times, rec, total_codes, total_visits);
        fused_bf16<<<(nslots + 3) / 4, 256, 0, stream>>>(
            all_codes, (const uint4*)embh, (const floatx4*)pad,
            (const floatx4*)tsc, rec, (floatx4*)d_out, nslots);
    } else {
        int* inv = (int*)ws;
        int* off = inv + nslots;
        (void)hipMemsetAsync(inv, 0xFF, (size_t)nslots * sizeof(int), stream);
        build_maps<<<(total_visits + 255) / 256, 256, 0, stream>>>(
            c2v, person, slot, inv, off, total_codes, total_visits);
        fused_f32<<<(nslots + 3) / 4, 256, 0, stream>>>(
            all_codes, times, (const floatx4*)emb, (const floatx4*)pad,
            (const floatx4*)tsc, inv, off, (floatx4*)d_out, nslots);
    }
}